// Round 19
// baseline (821.120 us; speedup 1.0000x reference)
//
#include <hip/hip_runtime.h>

#define HID 51
#define TLEN 1024
#define NBATCH 4
#define NW 13
#define NTH (NW * 64)    // 832 threads; wave w owns M-tile w

typedef _Float16 f16x8 __attribute__((ext_vector_type(8)));
typedef float    f32x4 __attribute__((ext_vector_type(4)));

#define LOG2E 1.4426950408889634f

__device__ __forceinline__ float frcp(float v){ return __builtin_amdgcn_rcpf(v); }
// input already scaled by log2e (or 2*log2e for tanh-gate)
__device__ __forceinline__ float sigm2(float v){ return frcp(1.f + __builtin_amdgcn_exp2f(-v)); }
__device__ __forceinline__ float tanh_c(float c){   // c in true domain
    return fmaf(2.f, frcp(1.f + __builtin_amdgcn_exp2f(-2.f*LOG2E*c)), -1.f);
}

// Fragment layout (validated R4): lane l reads 16B at half-index kb*512 + l*8
// covering k = 32*kb + 8*(l>>4) + 0..7, col = l&15.
// Writer (unit j, col n): half-index = (j>>5)<<9 + (n + ((j>>3)&3)*16)*8 + (j&7).
// C layout: lane (p, n) holds rows 4p..4p+3 of the tile = all 4 gates of unit
// je = 4m+p for column n -> epilogue is IN-LANE, no PRE buffer, no 2nd crossing.
// SINGLE PHASE per timestep, ONE barrier:
//   read h0(s-1), h1(s-2) frags -> MFMA L0(s) || MFMA L1(s-1)
//   -> in-lane gates -> write h0(s), h1(s-1) -> barrier.
// Projection: M-row 204 (tile 12) carries W_lin over the h1 K-range; its C value
// at step s = dot(W_lin, h1(s-2)) -> out(s-2).

__global__ __launch_bounds__(NTH)
void lstm2_mfma(const float* __restrict__ x,
                const float* __restrict__ W_ih0, const float* __restrict__ W_hh0,
                const float* __restrict__ b_ih0, const float* __restrict__ b_hh0,
                const float* __restrict__ W_ih1, const float* __restrict__ W_hh1,
                const float* __restrict__ b_ih1, const float* __restrict__ b_hh1,
                const float* __restrict__ W_lin, const float* __restrict__ b_lin,
                float* __restrict__ out)
{
    const int tid = threadIdx.x;
    const int w = tid >> 6;          // wave 0..12 = tile m
    const int l = tid & 63;
    const int n = l & 15;            // column slot (0-3 real batch)
    const int p = l >> 4;            // lane group 0..3

    __shared__ _Float16 H0[2][1024];
    __shared__ _Float16 H1[2][1024];
    __shared__ float XS[NBATCH][1032];   // staged x, padded rows

    for (int i = tid; i < 1024; i += NTH){
        H0[0][i] = (_Float16)0.f; H0[1][i] = (_Float16)0.f;
        H1[0][i] = (_Float16)0.f; H1[1][i] = (_Float16)0.f;
    }
    const long long bb = (long long)blockIdx.x * NBATCH;
    for (int i = tid; i < NBATCH*TLEN; i += NTH){
        const int r = i >> 10, c = i & 1023;
        XS[r][c] = x[(bb + r)*TLEN + c];
    }

    // ---- persistent fp16 weight fragments + C-init constants (tile m=w) ----
    f16x8 A0[2];   // W_hh0, K=64
    f16x8 A1[4];   // [0..1]=W_ih1 (k<64), [2..3]=W_hh1 (k64..127) + proj row 204
    {
        const int ar = 16*w + n;              // A-row = gate g = 4j + r
        const int aj = ar >> 2, arr = ar & 3;
        const bool rowv = (aj < HID);
        const int orow = arr*HID + aj;
        const float gsc = (arr == 2) ? 2.f*LOG2E : LOG2E;   // exp2-domain prescale
        #pragma unroll
        for (int kb=0; kb<2; ++kb){
            f16x8 hi;
            #pragma unroll
            for (int jj=0; jj<8; ++jj){
                const int k = kb*32 + 8*p + jj;
                const float wv = (rowv && k < HID) ? gsc * W_hh0[orow*HID + k] : 0.f;
                hi[jj] = (_Float16)wv;
            }
            A0[kb] = hi;
        }
        #pragma unroll
        for (int kb=0; kb<4; ++kb){
            f16x8 hi;
            #pragma unroll
            for (int jj=0; jj<8; ++jj){
                const int k = kb*32 + 8*p + jj;   // 0..127: [h0 ; h1]
                float wv = 0.f;
                if (rowv){
                    if (k < 64) { if (k < HID) wv = gsc * W_ih1[orow*HID + k]; }
                    else        { const int kk = k - 64; if (kk < HID) wv = gsc * W_hh1[orow*HID + kk]; }
                } else if (ar == 204 && k >= 64){ // projection row (unscaled!)
                    const int kk = k - 64; if (kk < HID) wv = W_lin[kk];
                }
                hi[jj] = (_Float16)wv;
            }
            A1[kb] = hi;
        }
    }
    const int je = 4*w + p;                     // unit owned by this lane
    const bool jev = (je < HID);
    const bool stA = (n < NBATCH) && jev;       // h-write mask
    f32x4 b0c, wx0c, b1c;
    #pragma unroll
    for (int r4=0; r4<4; ++r4){
        const float gs4 = (r4 == 2) ? 2.f*LOG2E : LOG2E;
        const int oe = r4*HID + je;
        b0c[r4]  = jev ? gs4 * (b_ih0[oe] + b_hh0[oe]) : 0.f;
        wx0c[r4] = jev ? gs4 * W_ih0[oe] : 0.f;
        b1c[r4]  = jev ? gs4 * (b_ih1[oe] + b_hh1[oe]) : 0.f;
    }
    const int widx = ((je>>5)<<9) + (n + ((je>>3)&3)*16)*8 + (je&7);
    const bool outm = (w == 12) && (p == 3) && (n < NBATCH);   // proj row 204
    const float blin = b_lin[0];
    float c0 = 0.f, c1 = 0.f;

    __syncthreads();

    // SINGLE-PHASE pipelined loop: one barrier per timestep.
    for (int s = 0; s <= TLEN + 1; ++s){
        const int pw = s & 1, prv = pw ^ 1;

        // fragments: h0(s-1), h1(s-2) — both published last phase
        f16x8 rb[2], r1[2];
        #pragma unroll
        for (int kb=0; kb<2; ++kb){
            rb[kb] = *reinterpret_cast<const f16x8*>(&H0[prv][kb*512 + l*8]);
            r1[kb] = *reinterpret_cast<const f16x8*>(&H1[prv][kb*512 + l*8]);
        }

        // ---- GEMM L1(s-1) + projection out(s-2) ----
        if (s >= 1){
            f32x4 b0 = b1c, b1 = {0.f,0.f,0.f,0.f};
            __builtin_amdgcn_s_setprio(1);
            b0 = __builtin_amdgcn_mfma_f32_16x16x32_f16(A1[0], rb[0], b0, 0,0,0);
            b1 = __builtin_amdgcn_mfma_f32_16x16x32_f16(A1[2], r1[0], b1, 0,0,0);
            b0 = __builtin_amdgcn_mfma_f32_16x16x32_f16(A1[1], rb[1], b0, 0,0,0);
            b1 = __builtin_amdgcn_mfma_f32_16x16x32_f16(A1[3], r1[1], b1, 0,0,0);
            __builtin_amdgcn_s_setprio(0);
            const f32x4 pre1 = b0 + b1;
            if (outm && s >= 2)
                out[(bb + n)*TLEN + (s-2)] = pre1[0] + blin;
            if (s <= TLEN){
                // in-lane EPI-L1 -> h1(s-1)
                const float gi = sigm2(pre1[0]);
                const float gf = sigm2(pre1[1]);
                const float gg = fmaf(2.f, sigm2(pre1[2]), -1.f);
                const float go = sigm2(pre1[3]);
                c1 = fmaf(gf, c1, gi*gg);
                const float hv = go * tanh_c(c1);
                if (stA) H1[pw][widx] = (_Float16)hv;
            }
        }

        // ---- GEMM L0(s) + in-lane EPI-L0 -> h0(s) ----
        if (s < TLEN){
            const float xv = XS[n & 3][s];
            f32x4 a = b0c;
            #pragma unroll
            for (int r4=0; r4<4; ++r4) a[r4] = fmaf(xv, wx0c[r4], a[r4]);
            __builtin_amdgcn_s_setprio(1);
            a = __builtin_amdgcn_mfma_f32_16x16x32_f16(A0[0], rb[0], a, 0,0,0);
            a = __builtin_amdgcn_mfma_f32_16x16x32_f16(A0[1], rb[1], a, 0,0,0);
            __builtin_amdgcn_s_setprio(0);
            const float gi = sigm2(a[0]);
            const float gf = sigm2(a[1]);
            const float gg = fmaf(2.f, sigm2(a[2]), -1.f);
            const float go = sigm2(a[3]);
            c0 = fmaf(gf, c0, gi*gg);
            const float hv = go * tanh_c(c0);
            if (stA) H0[pw][widx] = (_Float16)hv;
        }

        __syncthreads();   // the ONE barrier: h0(s), h1(s-1) published
    }
}

extern "C" void kernel_launch(void* const* d_in, const int* in_sizes, int n_in,
                              void* d_out, int out_size, void* d_ws, size_t ws_size,
                              hipStream_t stream) {
    const float* x     = (const float*)d_in[0];
    const float* W_ih0 = (const float*)d_in[1];
    const float* W_hh0 = (const float*)d_in[2];
    const float* b_ih0 = (const float*)d_in[3];
    const float* b_hh0 = (const float*)d_in[4];
    const float* W_ih1 = (const float*)d_in[5];
    const float* W_hh1 = (const float*)d_in[6];
    const float* b_ih1 = (const float*)d_in[7];
    const float* b_hh1 = (const float*)d_in[8];
    const float* W_lin = (const float*)d_in[9];
    const float* b_lin = (const float*)d_in[10];
    float* out = (float*)d_out;

    const int B = in_sizes[0] / TLEN;
    lstm2_mfma<<<dim3(B / NBATCH), dim3(NTH), 0, stream>>>(
        x, W_ih0, W_hh0, b_ih0, b_hh0, W_ih1, W_hh1, b_ih1, b_hh1, W_lin, b_lin, out);
}

// Round 20
// 756.052 us; speedup vs baseline: 1.0861x; 1.0861x over previous
//
#include <hip/hip_runtime.h>

#define HID 51
#define TLEN 1024
#define NBATCH 4
#define NW 7
#define NTH (NW * 64)    // 448 threads; each wave owns tiles {w, w+7}

typedef _Float16 f16x8 __attribute__((ext_vector_type(8)));
typedef float    f32x4 __attribute__((ext_vector_type(4)));

#define LOG2E 1.4426950408889634f

__device__ __forceinline__ float frcp(float v){ return __builtin_amdgcn_rcpf(v); }
// input already scaled by log2e (or 2*log2e for tanh-gate)
__device__ __forceinline__ float sigm2(float v){ return frcp(1.f + __builtin_amdgcn_exp2f(-v)); }
__device__ __forceinline__ float tanh_c(float c){   // c in true domain
    return fmaf(2.f, frcp(1.f + __builtin_amdgcn_exp2f(-2.f*LOG2E*c)), -1.f);
}

// Fragment layout (validated R4): lane l reads 16B at half-index kb*512 + l*8
// covering k = 32*kb + 8*(l>>4) + 0..7, col = l&15.
// Writer (unit j, col n): half-index = (j>>5)<<9 + (n + ((j>>3)&3)*16)*8 + (j&7).
// Balanced 2-phase pipeline (R17) + LDS diet: B-fragment reads exec-masked to
// real batch columns (n<4) — dead lanes keep zeroed regs; their MFMA columns
// (C cols 4-15) are never read, and MFMA columns are independent.
//   Phase A(s): GEMM L0(s)  ||  EPI-L1 on PRE1(s-2) -> h1(s-2)
//   Phase B(s): GEMM L1(s-1) ||  EPI-L0 on PRE0(s)  -> h0(s)
// Projection: M-row 204 (tile 12) carries W_lin over the h1 K-range.

__global__ __launch_bounds__(NTH)
void lstm2_mfma(const float* __restrict__ x,
                const float* __restrict__ W_ih0, const float* __restrict__ W_hh0,
                const float* __restrict__ b_ih0, const float* __restrict__ b_hh0,
                const float* __restrict__ W_ih1, const float* __restrict__ W_hh1,
                const float* __restrict__ b_ih1, const float* __restrict__ b_hh1,
                const float* __restrict__ W_lin, const float* __restrict__ b_lin,
                float* __restrict__ out)
{
    const int tid = threadIdx.x;
    const int w = tid >> 6;          // wave 0..6; tiles {w, w+7}
    const int l = tid & 63;
    const int n = l & 15;            // column slot (0-3 real batch)
    const int p = l >> 4;            // lane group 0..3
    const bool rlane = (n < NBATCH); // lanes whose B-column is real

    __shared__ _Float16 H0[2][1024];
    __shared__ _Float16 H1[2][1024];
    __shared__ __align__(16) float PRE0[HID*NBATCH*4];    // 204 x f32x4
    __shared__ __align__(16) float PRE1[HID*NBATCH*4];    // 204 x f32x4
    __shared__ float XS[NBATCH][1032];                    // staged x, padded rows

    for (int i = tid; i < 1024; i += NTH){
        H0[0][i] = (_Float16)0.f; H0[1][i] = (_Float16)0.f;
        H1[0][i] = (_Float16)0.f; H1[1][i] = (_Float16)0.f;
    }
    const long long bb = (long long)blockIdx.x * NBATCH;
    for (int i = tid; i < NBATCH*TLEN; i += NTH){
        const int r = i >> 10, c = i & 1023;
        XS[r][c] = x[(bb + r)*TLEN + c];
    }

    // ---- GEMM-role: persistent fp16 weight fragments + C-init consts ----
    f16x8 A0[2][2];   // W_hh0, K=64
    f16x8 A1[2][4];   // [0..1]=W_ih1 (k<64), [2..3]=W_hh1 (k64..127) + proj row 204
    f32x4 b0c[2], wx0c[2], b1c[2];
    int  jet[2]; bool stAt[2];
    #pragma unroll
    for (int t=0; t<2; ++t){
        const int tile = w + 7*t;             // 0..13 (13 = zero dummy)
        const int ar = 16*tile + n;           // A-row = gate g = 4j + r
        const int aj = ar >> 2, arr = ar & 3;
        const bool rowv = (aj < HID);
        const int orow = arr*HID + aj;
        const float gsc = (arr == 2) ? 2.f*LOG2E : LOG2E;
        #pragma unroll
        for (int kb=0; kb<2; ++kb){
            f16x8 hi;
            #pragma unroll
            for (int jj=0; jj<8; ++jj){
                const int k = kb*32 + 8*p + jj;
                const float wv = (rowv && k < HID) ? gsc * W_hh0[orow*HID + k] : 0.f;
                hi[jj] = (_Float16)wv;
            }
            A0[t][kb] = hi;
        }
        #pragma unroll
        for (int kb=0; kb<4; ++kb){
            f16x8 hi;
            #pragma unroll
            for (int jj=0; jj<8; ++jj){
                const int k = kb*32 + 8*p + jj;   // 0..127: [h0 ; h1]
                float wv = 0.f;
                if (rowv){
                    if (k < 64) { if (k < HID) wv = gsc * W_ih1[orow*HID + k]; }
                    else        { const int kk = k - 64; if (kk < HID) wv = gsc * W_hh1[orow*HID + kk]; }
                } else if (ar == 204 && k >= 64){ // projection row (unscaled!)
                    const int kk = k - 64; if (kk < HID) wv = W_lin[kk];
                }
                hi[jj] = (_Float16)wv;
            }
            A1[t][kb] = hi;
        }
        jet[t]  = 4*tile + p;
        stAt[t] = rlane && (jet[t] < HID);
        const bool jev = (jet[t] < HID) && (tile < 13);
        #pragma unroll
        for (int r4=0; r4<4; ++r4){
            const float gs4 = (r4 == 2) ? 2.f*LOG2E : LOG2E;
            const int oe = r4*HID + jet[t];
            b0c[t][r4]  = jev ? gs4 * (b_ih0[oe] + b_hh0[oe]) : 0.f;
            wx0c[t][r4] = jev ? gs4 * W_ih0[oe] : 0.f;
            b1c[t][r4]  = jev ? gs4 * (b_ih1[oe] + b_hh1[oe]) : 0.f;
        }
    }
    const bool outm = (w == 5) && (p == 3) && rlane;   // tile 12, row 204
    const float blin = b_lin[0];

    // ---- epilogue-role: one pure-gate chain per lane ----
    const int q = tid;
    const bool eact = (q < 2*HID*NBATCH);     // 408 chains
    const int lay = (q >= HID*NBATCH) ? 1 : 0;  // 0: phase B, 1: phase A
    const int qq = q - lay*HID*NBATCH;
    const int jq = qq >> 2, nq = qq & 3;
    const int widxq = ((jq>>5)<<9) + (nq + ((jq>>3)&3)*16)*8 + (jq&7);
    float cst = 0.f;    // cell state of this lane's (layer, unit, batch)

    // B-fragment registers: zero-init once; only real-column lanes update them.
    f16x8 rb[2], r1[2];
    #pragma unroll
    for (int kb=0; kb<2; ++kb){
        #pragma unroll
        for (int jj=0; jj<8; ++jj){ rb[kb][jj] = (_Float16)0.f; r1[kb][jj] = (_Float16)0.f; }
    }

    __syncthreads();

    for (int s = 0; s <= TLEN + 1; ++s){
        const int pw = s & 1, prv = pw ^ 1;

        // ================= PHASE A =================
        // rb = h0(s-1) fragments — masked to real columns (4x less LDS traffic)
        if (rlane){
            #pragma unroll
            for (int kb=0; kb<2; ++kb)
                rb[kb] = *reinterpret_cast<const f16x8*>(&H0[prv][kb*512 + l*8]);
        }

        if (s < TLEN){
            const float xv = XS[n & 3][s];
            f32x4 a0 = b0c[0], a1 = b0c[1];
            #pragma unroll
            for (int r4=0; r4<4; ++r4){
                a0[r4] = fmaf(xv, wx0c[0][r4], a0[r4]);
                a1[r4] = fmaf(xv, wx0c[1][r4], a1[r4]);
            }
            __builtin_amdgcn_s_setprio(1);
            a0 = __builtin_amdgcn_mfma_f32_16x16x32_f16(A0[0][0], rb[0], a0, 0,0,0);
            a1 = __builtin_amdgcn_mfma_f32_16x16x32_f16(A0[1][0], rb[0], a1, 0,0,0);
            a0 = __builtin_amdgcn_mfma_f32_16x16x32_f16(A0[0][1], rb[1], a0, 0,0,0);
            a1 = __builtin_amdgcn_mfma_f32_16x16x32_f16(A0[1][1], rb[1], a1, 0,0,0);
            __builtin_amdgcn_s_setprio(0);
            if (stAt[0]) *reinterpret_cast<f32x4*>(&PRE0[(jet[0]*NBATCH + n)*4]) = a0;
            if (stAt[1]) *reinterpret_cast<f32x4*>(&PRE0[(jet[1]*NBATCH + n)*4]) = a1;
        }
        // EPI-L1: gates of L1(s-2) from PRE1 -> h1(s-2) into H1[s&1]
        if (eact && lay == 1 && s >= 2 && s <= TLEN + 1){
            const f32x4 pre = *reinterpret_cast<const f32x4*>(&PRE1[qq*4]);
            const float gi = sigm2(pre[0]);
            const float gf = sigm2(pre[1]);
            const float gg = fmaf(2.f, sigm2(pre[2]), -1.f);
            const float go = sigm2(pre[3]);
            cst = fmaf(gf, cst, gi*gg);
            H1[pw][widxq] = (_Float16)(go * tanh_c(cst));
        }
        __syncthreads();   // #1: PRE0(s), h1(s-2) visible

        // ================= PHASE B =================
        if (s >= 1){
            // r1 = h1(s-2) fragments (just published) — masked to real columns
            if (rlane){
                #pragma unroll
                for (int kb=0; kb<2; ++kb)
                    r1[kb] = *reinterpret_cast<const f16x8*>(&H1[pw][kb*512 + l*8]);
            }
            __builtin_amdgcn_s_setprio(1);
            f32x4 b0 = b1c[0], b1 = {0.f,0.f,0.f,0.f};
            f32x4 c0 = b1c[1], c1 = {0.f,0.f,0.f,0.f};
            b0 = __builtin_amdgcn_mfma_f32_16x16x32_f16(A1[0][0], rb[0], b0, 0,0,0);
            c0 = __builtin_amdgcn_mfma_f32_16x16x32_f16(A1[1][0], rb[0], c0, 0,0,0);
            b1 = __builtin_amdgcn_mfma_f32_16x16x32_f16(A1[0][2], r1[0], b1, 0,0,0);
            c1 = __builtin_amdgcn_mfma_f32_16x16x32_f16(A1[1][2], r1[0], c1, 0,0,0);
            b0 = __builtin_amdgcn_mfma_f32_16x16x32_f16(A1[0][1], rb[1], b0, 0,0,0);
            c0 = __builtin_amdgcn_mfma_f32_16x16x32_f16(A1[1][1], rb[1], c0, 0,0,0);
            b1 = __builtin_amdgcn_mfma_f32_16x16x32_f16(A1[0][3], r1[1], b1, 0,0,0);
            c1 = __builtin_amdgcn_mfma_f32_16x16x32_f16(A1[1][3], r1[1], c1, 0,0,0);
            __builtin_amdgcn_s_setprio(0);
            const f32x4 preT0 = b0 + b1;
            const f32x4 preT1 = c0 + c1;
            if (s <= TLEN){
                if (stAt[0]) *reinterpret_cast<f32x4*>(&PRE1[(jet[0]*NBATCH + n)*4]) = preT0;
                if (stAt[1]) *reinterpret_cast<f32x4*>(&PRE1[(jet[1]*NBATCH + n)*4]) = preT1;
            }
            if (outm && s >= 2)
                out[(bb + n)*TLEN + (s-2)] = preT1[0] + blin;   // proj row 204
        }
        // EPI-L0: gates of L0(s) from PRE0 -> h0(s) into H0[s&1]
        if (eact && lay == 0 && s < TLEN){
            const f32x4 pre = *reinterpret_cast<const f32x4*>(&PRE0[qq*4]);
            const float gi = sigm2(pre[0]);
            const float gf = sigm2(pre[1]);
            const float gg = fmaf(2.f, sigm2(pre[2]), -1.f);
            const float go = sigm2(pre[3]);
            cst = fmaf(gf, cst, gi*gg);
            H0[pw][widxq] = (_Float16)(go * tanh_c(cst));
        }
        __syncthreads();   // #2: PRE1(s-1), h0(s) visible
    }
}

extern "C" void kernel_launch(void* const* d_in, const int* in_sizes, int n_in,
                              void* d_out, int out_size, void* d_ws, size_t ws_size,
                              hipStream_t stream) {
    const float* x     = (const float*)d_in[0];
    const float* W_ih0 = (const float*)d_in[1];
    const float* W_hh0 = (const float*)d_in[2];
    const float* b_ih0 = (const float*)d_in[3];
    const float* b_hh0 = (const float*)d_in[4];
    const float* W_ih1 = (const float*)d_in[5];
    const float* W_hh1 = (const float*)d_in[6];
    const float* b_ih1 = (const float*)d_in[7];
    const float* b_hh1 = (const float*)d_in[8];
    const float* W_lin = (const float*)d_in[9];
    const float* b_lin = (const float*)d_in[10];
    float* out = (float*)d_out;

    const int B = in_sizes[0] / TLEN;
    lstm2_mfma<<<dim3(B / NBATCH), dim3(NTH), 0, stream>>>(
        x, W_ih0, W_hh0, b_ih0, b_hh0, W_ih1, W_hh1, b_ih1, b_hh1, W_lin, b_lin, out);
}

// Round 21
// 722.994 us; speedup vs baseline: 1.1357x; 1.0457x over previous
//
#include <hip/hip_runtime.h>

#define HID 51
#define TLEN 1024
#define NBATCH 4
#define NW 7
#define NTH (NW * 64)    // 448 threads; each wave owns tiles {w, w+7}

typedef _Float16 f16x8 __attribute__((ext_vector_type(8)));
typedef float    f32x4 __attribute__((ext_vector_type(4)));

#define LOG2E 1.4426950408889634f

__device__ __forceinline__ float frcp(float v){ return __builtin_amdgcn_rcpf(v); }
// input already scaled by log2e (or 2*log2e for tanh-gate)
__device__ __forceinline__ float sigm2(float v){ return frcp(1.f + __builtin_amdgcn_exp2f(-v)); }
__device__ __forceinline__ float tanh_c(float c){   // c in true domain
    return fmaf(2.f, frcp(1.f + __builtin_amdgcn_exp2f(-2.f*LOG2E*c)), -1.f);
}

// Fragment layout (validated R4): lane l reads 16B at half-index kb*512 + l*8
// covering k = 32*kb + 8*(l>>4) + 0..7, col = l&15.
// Writer (unit j, col n): half-index = (j>>5)<<9 + (n + ((j>>3)&3)*16)*8 + (j&7).
// Balanced 2-phase pipeline (R17):
//   Phase A(s): GEMM L0(s)  ||  EPI-L1 on PRE1(s-2) -> h1(s-2)
//   Phase B(s): GEMM L1(s-1) ||  EPI-L0 on PRE0(s)  -> h0(s)
// KEY CHANGE vs R17: NO global ops inside the loop. The projection output goes
// to an LDS OUT buffer; one coalesced flush after the loop. This removes the
// compiler's vmcnt(0) drain (global store ack, ~200-400cyc) from the per-step
// barrier critical path.
// Projection: M-row 204 (tile 12) carries W_lin over the h1 K-range.

__global__ __launch_bounds__(NTH)
void lstm2_mfma(const float* __restrict__ x,
                const float* __restrict__ W_ih0, const float* __restrict__ W_hh0,
                const float* __restrict__ b_ih0, const float* __restrict__ b_hh0,
                const float* __restrict__ W_ih1, const float* __restrict__ W_hh1,
                const float* __restrict__ b_ih1, const float* __restrict__ b_hh1,
                const float* __restrict__ W_lin, const float* __restrict__ b_lin,
                float* __restrict__ out)
{
    const int tid = threadIdx.x;
    const int w = tid >> 6;          // wave 0..6; tiles {w, w+7}
    const int l = tid & 63;
    const int n = l & 15;            // column slot (0-3 real batch)
    const int p = l >> 4;            // lane group 0..3

    __shared__ _Float16 H0[2][1024];
    __shared__ _Float16 H1[2][1024];
    __shared__ __align__(16) float PRE0[HID*NBATCH*4];    // 204 x f32x4
    __shared__ __align__(16) float PRE1[HID*NBATCH*4];    // 204 x f32x4
    __shared__ float XS[NBATCH][1032];                    // staged x, padded rows
    __shared__ float OUT[NBATCH][TLEN];                   // staged outputs

    for (int i = tid; i < 1024; i += NTH){
        H0[0][i] = (_Float16)0.f; H0[1][i] = (_Float16)0.f;
        H1[0][i] = (_Float16)0.f; H1[1][i] = (_Float16)0.f;
    }
    const long long bb = (long long)blockIdx.x * NBATCH;
    for (int i = tid; i < NBATCH*TLEN; i += NTH){
        const int r = i >> 10, c = i & 1023;
        XS[r][c] = x[(bb + r)*TLEN + c];
    }

    // ---- GEMM-role: persistent fp16 weight fragments + C-init consts ----
    f16x8 A0[2][2];   // W_hh0, K=64
    f16x8 A1[2][4];   // [0..1]=W_ih1 (k<64), [2..3]=W_hh1 (k64..127) + proj row 204
    f32x4 b0c[2], wx0c[2], b1c[2];
    int  jet[2]; bool stAt[2];
    #pragma unroll
    for (int t=0; t<2; ++t){
        const int tile = w + 7*t;             // 0..13 (13 = zero dummy)
        const int ar = 16*tile + n;           // A-row = gate g = 4j + r
        const int aj = ar >> 2, arr = ar & 3;
        const bool rowv = (aj < HID);
        const int orow = arr*HID + aj;
        const float gsc = (arr == 2) ? 2.f*LOG2E : LOG2E;
        #pragma unroll
        for (int kb=0; kb<2; ++kb){
            f16x8 hi;
            #pragma unroll
            for (int jj=0; jj<8; ++jj){
                const int k = kb*32 + 8*p + jj;
                const float wv = (rowv && k < HID) ? gsc * W_hh0[orow*HID + k] : 0.f;
                hi[jj] = (_Float16)wv;
            }
            A0[t][kb] = hi;
        }
        #pragma unroll
        for (int kb=0; kb<4; ++kb){
            f16x8 hi;
            #pragma unroll
            for (int jj=0; jj<8; ++jj){
                const int k = kb*32 + 8*p + jj;   // 0..127: [h0 ; h1]
                float wv = 0.f;
                if (rowv){
                    if (k < 64) { if (k < HID) wv = gsc * W_ih1[orow*HID + k]; }
                    else        { const int kk = k - 64; if (kk < HID) wv = gsc * W_hh1[orow*HID + kk]; }
                } else if (ar == 204 && k >= 64){ // projection row (unscaled!)
                    const int kk = k - 64; if (kk < HID) wv = W_lin[kk];
                }
                hi[jj] = (_Float16)wv;
            }
            A1[t][kb] = hi;
        }
        jet[t]  = 4*tile + p;
        stAt[t] = (n < NBATCH) && (jet[t] < HID);
        const bool jev = (jet[t] < HID) && (tile < 13);
        #pragma unroll
        for (int r4=0; r4<4; ++r4){
            const float gs4 = (r4 == 2) ? 2.f*LOG2E : LOG2E;
            const int oe = r4*HID + jet[t];
            b0c[t][r4]  = jev ? gs4 * (b_ih0[oe] + b_hh0[oe]) : 0.f;
            wx0c[t][r4] = jev ? gs4 * W_ih0[oe] : 0.f;
            b1c[t][r4]  = jev ? gs4 * (b_ih1[oe] + b_hh1[oe]) : 0.f;
        }
    }
    const bool outm = (w == 5) && (p == 3) && (n < NBATCH);   // tile 12, row 204
    const float blin = b_lin[0];

    // ---- epilogue-role: one pure-gate chain per lane ----
    const int q = tid;
    const bool eact = (q < 2*HID*NBATCH);     // 408 chains
    const int lay = (q >= HID*NBATCH) ? 1 : 0;  // 0: phase B, 1: phase A
    const int qq = q - lay*HID*NBATCH;
    const int jq = qq >> 2, nq = qq & 3;
    const int widxq = ((jq>>5)<<9) + (nq + ((jq>>3)&3)*16)*8 + (jq&7);
    float cst = 0.f;    // cell state of this lane's (layer, unit, batch)

    __syncthreads();

    for (int s = 0; s <= TLEN + 1; ++s){
        const int pw = s & 1, prv = pw ^ 1;

        // ================= PHASE A =================
        // rb = h0(s-1) fragments — used by L0 now AND L1 in phase B (reg-carried)
        f16x8 rb[2];
        #pragma unroll
        for (int kb=0; kb<2; ++kb)
            rb[kb] = *reinterpret_cast<const f16x8*>(&H0[prv][kb*512 + l*8]);

        if (s < TLEN){
            const float xv = XS[n & 3][s];
            f32x4 a0 = b0c[0], a1 = b0c[1];
            #pragma unroll
            for (int r4=0; r4<4; ++r4){
                a0[r4] = fmaf(xv, wx0c[0][r4], a0[r4]);
                a1[r4] = fmaf(xv, wx0c[1][r4], a1[r4]);
            }
            __builtin_amdgcn_s_setprio(1);
            a0 = __builtin_amdgcn_mfma_f32_16x16x32_f16(A0[0][0], rb[0], a0, 0,0,0);
            a1 = __builtin_amdgcn_mfma_f32_16x16x32_f16(A0[1][0], rb[0], a1, 0,0,0);
            a0 = __builtin_amdgcn_mfma_f32_16x16x32_f16(A0[0][1], rb[1], a0, 0,0,0);
            a1 = __builtin_amdgcn_mfma_f32_16x16x32_f16(A0[1][1], rb[1], a1, 0,0,0);
            __builtin_amdgcn_s_setprio(0);
            if (stAt[0]) *reinterpret_cast<f32x4*>(&PRE0[(jet[0]*NBATCH + n)*4]) = a0;
            if (stAt[1]) *reinterpret_cast<f32x4*>(&PRE0[(jet[1]*NBATCH + n)*4]) = a1;
        }
        // EPI-L1: gates of L1(s-2) from PRE1 -> h1(s-2) into H1[s&1]
        if (eact && lay == 1 && s >= 2 && s <= TLEN + 1){
            const f32x4 pre = *reinterpret_cast<const f32x4*>(&PRE1[qq*4]);
            const float gi = sigm2(pre[0]);
            const float gf = sigm2(pre[1]);
            const float gg = fmaf(2.f, sigm2(pre[2]), -1.f);
            const float go = sigm2(pre[3]);
            cst = fmaf(gf, cst, gi*gg);
            H1[pw][widxq] = (_Float16)(go * tanh_c(cst));
        }
        __syncthreads();   // #1: PRE0(s), h1(s-2) visible (LDS-only drain)

        // ================= PHASE B =================
        if (s >= 1){
            // r1 = h1(s-2) fragments (just published)
            f16x8 r1[2];
            #pragma unroll
            for (int kb=0; kb<2; ++kb)
                r1[kb] = *reinterpret_cast<const f16x8*>(&H1[pw][kb*512 + l*8]);
            __builtin_amdgcn_s_setprio(1);
            f32x4 b0 = b1c[0], b1 = {0.f,0.f,0.f,0.f};
            f32x4 c0 = b1c[1], c1 = {0.f,0.f,0.f,0.f};
            b0 = __builtin_amdgcn_mfma_f32_16x16x32_f16(A1[0][0], rb[0], b0, 0,0,0);
            c0 = __builtin_amdgcn_mfma_f32_16x16x32_f16(A1[1][0], rb[0], c0, 0,0,0);
            b1 = __builtin_amdgcn_mfma_f32_16x16x32_f16(A1[0][2], r1[0], b1, 0,0,0);
            c1 = __builtin_amdgcn_mfma_f32_16x16x32_f16(A1[1][2], r1[0], c1, 0,0,0);
            b0 = __builtin_amdgcn_mfma_f32_16x16x32_f16(A1[0][1], rb[1], b0, 0,0,0);
            c0 = __builtin_amdgcn_mfma_f32_16x16x32_f16(A1[1][1], rb[1], c0, 0,0,0);
            b1 = __builtin_amdgcn_mfma_f32_16x16x32_f16(A1[0][3], r1[1], b1, 0,0,0);
            c1 = __builtin_amdgcn_mfma_f32_16x16x32_f16(A1[1][3], r1[1], c1, 0,0,0);
            __builtin_amdgcn_s_setprio(0);
            const f32x4 preT0 = b0 + b1;
            const f32x4 preT1 = c0 + c1;
            if (s <= TLEN){
                if (stAt[0]) *reinterpret_cast<f32x4*>(&PRE1[(jet[0]*NBATCH + n)*4]) = preT0;
                if (stAt[1]) *reinterpret_cast<f32x4*>(&PRE1[(jet[1]*NBATCH + n)*4]) = preT1;
            }
            if (outm && s >= 2)
                OUT[n][s-2] = preT1[0] + blin;   // LDS, not global!
        }
        // EPI-L0: gates of L0(s) from PRE0 -> h0(s) into H0[s&1]
        if (eact && lay == 0 && s < TLEN){
            const f32x4 pre = *reinterpret_cast<const f32x4*>(&PRE0[qq*4]);
            const float gi = sigm2(pre[0]);
            const float gf = sigm2(pre[1]);
            const float gg = fmaf(2.f, sigm2(pre[2]), -1.f);
            const float go = sigm2(pre[3]);
            cst = fmaf(gf, cst, gi*gg);
            H0[pw][widxq] = (_Float16)(go * tanh_c(cst));
        }
        __syncthreads();   // #2: PRE1(s-1), h0(s) visible (LDS-only drain)
    }

    // cooperative coalesced flush of staged outputs
    for (int i = tid; i < NBATCH*TLEN; i += NTH){
        const int r = i >> 10, c = i & 1023;
        out[(bb + r)*TLEN + c] = OUT[r][c];
    }
}

extern "C" void kernel_launch(void* const* d_in, const int* in_sizes, int n_in,
                              void* d_out, int out_size, void* d_ws, size_t ws_size,
                              hipStream_t stream) {
    const float* x     = (const float*)d_in[0];
    const float* W_ih0 = (const float*)d_in[1];
    const float* W_hh0 = (const float*)d_in[2];
    const float* b_ih0 = (const float*)d_in[3];
    const float* b_hh0 = (const float*)d_in[4];
    const float* W_ih1 = (const float*)d_in[5];
    const float* W_hh1 = (const float*)d_in[6];
    const float* b_ih1 = (const float*)d_in[7];
    const float* b_hh1 = (const float*)d_in[8];
    const float* W_lin = (const float*)d_in[9];
    const float* b_lin = (const float*)d_in[10];
    float* out = (float*)d_out;

    const int B = in_sizes[0] / TLEN;
    lstm2_mfma<<<dim3(B / NBATCH), dim3(NTH), 0, stream>>>(
        x, W_ih0, W_hh0, b_ih0, b_hh0, W_ih1, W_hh1, b_ih1, b_hh1, W_lin, b_lin, out);
}